// Round 1
// baseline (1228.197 us; speedup 1.0000x reference)
//
#include <hip/hip_runtime.h>
#include <hip/hip_bf16.h>
#include <stdint.h>

// ---------------------------------------------------------------------------
// DeepseekV2 decoder layer (rmsnorm -> q/o proj + residual -> rmsnorm ->
// gate/up (SiLU) -> down + residual) on MI355X, bf16 MFMA path.
// Tolerance is 2% relative (harness printed threshold = 0.02*absmax(ref)),
// so bf16 GEMMs with fp32 accumulation are safe.
// ---------------------------------------------------------------------------

typedef __bf16 bf16;
typedef bf16 bf16x8 __attribute__((ext_vector_type(8)));
typedef bf16 bf16x4 __attribute__((ext_vector_type(4)));
typedef float f32x4 __attribute__((ext_vector_type(4)));

#define HID     2048
#define TOK     4096
#define INTER   10944
#define INTER_P 11008   // padded to multiple of 128; pad region is zeros
#define BK      32

// async global->LDS, 16B per lane. LDS dest must be wave-uniform base +
// lane*16 (our chunk layout is lane-contiguous, so this holds).
__device__ __forceinline__ void gload_lds16(const bf16* g, bf16* l) {
    __builtin_amdgcn_global_load_lds(
        (const __attribute__((address_space(1))) void*)g,
        (__attribute__((address_space(3))) void*)l, 16, 0, 0);
}

// ---------------------------------------------------------------------------
// fp32 -> bf16 conversion, linear copy with zero tail (row-padded Wg/Wu: the
// pad rows are appended at the end of the linear layout, so tail-zeroing is
// exactly row padding). n_src, n_dst multiples of 4.
// ---------------------------------------------------------------------------
__global__ __launch_bounds__(256) void conv_pad(const float* __restrict__ src,
                                                bf16* __restrict__ dst,
                                                int n_src, int n_dst) {
    int i = (blockIdx.x * 256 + threadIdx.x) * 4;
    if (i >= n_dst) return;
    float4 v = make_float4(0.f, 0.f, 0.f, 0.f);
    if (i < n_src) v = *(const float4*)(src + i);
    bf16x4 o;
    o[0] = (bf16)v.x; o[1] = (bf16)v.y; o[2] = (bf16)v.z; o[3] = (bf16)v.w;
    *(bf16x4*)(dst + i) = o;
}

// Wd [2048,10944] -> [2048,11008], columns padded with zeros.
__global__ __launch_bounds__(256) void conv_wd(const float* __restrict__ src,
                                               bf16* __restrict__ dst) {
    int i = (blockIdx.x * 256 + threadIdx.x) * 4;
    if (i >= HID * INTER_P) return;
    int row = i / INTER_P;
    int col = i - row * INTER_P;
    float4 v = make_float4(0.f, 0.f, 0.f, 0.f);
    if (col < INTER)  // 10944 % 4 == 0, so a 4-chunk never straddles the pad
        v = *(const float4*)(src + (size_t)row * INTER + col);
    bf16x4 o;
    o[0] = (bf16)v.x; o[1] = (bf16)v.y; o[2] = (bf16)v.z; o[3] = (bf16)v.w;
    *(bf16x4*)(dst + i) = o;
}

// ---------------------------------------------------------------------------
// RMSNorm: one block per row of 2048 fp32, emit bf16 * w.
// ---------------------------------------------------------------------------
__global__ __launch_bounds__(256) void rmsnorm_k(const float* __restrict__ x,
                                                 const float* __restrict__ w,
                                                 bf16* __restrict__ out) {
    const int row = blockIdx.x;
    const int tid = threadIdx.x;
    const float* xr = x + (size_t)row * HID + tid * 8;
    float4 v0 = *(const float4*)(xr);
    float4 v1 = *(const float4*)(xr + 4);
    float s = v0.x * v0.x + v0.y * v0.y + v0.z * v0.z + v0.w * v0.w +
              v1.x * v1.x + v1.y * v1.y + v1.z * v1.z + v1.w * v1.w;
    #pragma unroll
    for (int o = 32; o > 0; o >>= 1) s += __shfl_down(s, o);
    __shared__ float red[4];
    if ((tid & 63) == 0) red[tid >> 6] = s;
    __syncthreads();
    float tot = red[0] + red[1] + red[2] + red[3];
    float scale = rsqrtf(tot * (1.0f / (float)HID) + 1e-6f);
    float4 w0 = *(const float4*)(w + tid * 8);
    float4 w1 = *(const float4*)(w + tid * 8 + 4);
    bf16x8 o8;
    o8[0] = (bf16)(v0.x * scale * w0.x);
    o8[1] = (bf16)(v0.y * scale * w0.y);
    o8[2] = (bf16)(v0.z * scale * w0.z);
    o8[3] = (bf16)(v0.w * scale * w0.w);
    o8[4] = (bf16)(v1.x * scale * w1.x);
    o8[5] = (bf16)(v1.y * scale * w1.y);
    o8[6] = (bf16)(v1.z * scale * w1.z);
    o8[7] = (bf16)(v1.w * scale * w1.w);
    *(bf16x8*)(out + (size_t)row * HID + tid * 8) = o8;
}

// ---------------------------------------------------------------------------
// m97-style GEMM: C[M,N] = A[M,K] * W[N,K]^T  (both row-major, bf16, K-major
// contiguous => both operands load identically).
// 128x128 block tile, BK=32, 256 threads = 4 waves in 2x2 of 64x64.
// EPI=0: store bf16. EPI=1: store fp32 res[idx] + acc.
// ---------------------------------------------------------------------------
template <int EPI>
__global__ __launch_bounds__(256, 3) void gemm_bt(const bf16* __restrict__ A,
                                                  const bf16* __restrict__ W,
                                                  const float* __restrict__ res,
                                                  void* __restrict__ out,
                                                  int N, int K) {
    __shared__ bf16 lA[128 * BK];
    __shared__ bf16 lW[128 * BK];
    const int tid = threadIdx.x;
    const int rowBase = blockIdx.y * 128;
    const int colBase = blockIdx.x * 128;
    const int wave = tid >> 6, lane = tid & 63;
    const int wm = (wave >> 1) * 64, wn = (wave & 1) * 64;
    const int lr = lane & 15, kq = lane >> 4;

    f32x4 acc[4][4] = {};
    const bf16* Ab = A + (size_t)rowBase * K;
    const bf16* Wb = W + (size_t)colBase * K;

    for (int k0 = 0; k0 < K; k0 += BK) {
        #pragma unroll
        for (int it = 0; it < 2; ++it) {
            int c = tid + it * 256;        // 512 16B-chunks per 8KB tile
            int r = c >> 2, sseg = c & 3;
            gload_lds16(Ab + (size_t)r * K + k0 + sseg * 8, &lA[c * 8]);
            gload_lds16(Wb + (size_t)r * K + k0 + sseg * 8, &lW[c * 8]);
        }
        __syncthreads();   // compiler drains vmcnt before s_barrier
        bf16x8 af[4], wf[4];
        #pragma unroll
        for (int i = 0; i < 4; ++i)
            af[i] = *(const bf16x8*)&lA[(wm + i * 16 + lr) * BK + kq * 8];
        #pragma unroll
        for (int i = 0; i < 4; ++i)
            wf[i] = *(const bf16x8*)&lW[(wn + i * 16 + lr) * BK + kq * 8];
        #pragma unroll
        for (int mi = 0; mi < 4; ++mi)
            #pragma unroll
            for (int ni = 0; ni < 4; ++ni)
                acc[mi][ni] = __builtin_amdgcn_mfma_f32_16x16x32_bf16(
                    af[mi], wf[ni], acc[mi][ni], 0, 0, 0);
        __syncthreads();
    }
    // C/D layout: col = lane&15, row = (lane>>4)*4 + reg   [m89/m91 verified]
    const int rq = lane >> 4, cn = lane & 15;
    #pragma unroll
    for (int mi = 0; mi < 4; ++mi) {
        #pragma unroll
        for (int ni = 0; ni < 4; ++ni) {
            int col = colBase + wn + ni * 16 + cn;
            #pragma unroll
            for (int r = 0; r < 4; ++r) {
                int row = rowBase + wm + mi * 16 + rq * 4 + r;
                size_t idx = (size_t)row * N + col;
                float v = acc[mi][ni][r];
                if (EPI == 0) ((bf16*)out)[idx] = (bf16)v;
                else          ((float*)out)[idx] = res[idx] + v;
            }
        }
    }
}

// ---------------------------------------------------------------------------
// Fused gate/up: gu[t,i] = silu(A·Wg^T) * (A·Wu^T), bf16 out. Shares the
// A-tile, doubles accumulators. N = INTER_P (pad cols come out exactly 0).
// ---------------------------------------------------------------------------
__global__ __launch_bounds__(256, 2) void gemm_gu_k(const bf16* __restrict__ A,
                                                    const bf16* __restrict__ Wg,
                                                    const bf16* __restrict__ Wu,
                                                    bf16* __restrict__ out,
                                                    int N, int K) {
    __shared__ bf16 lA[128 * BK];
    __shared__ bf16 lG[128 * BK];
    __shared__ bf16 lU[128 * BK];
    const int tid = threadIdx.x;
    const int rowBase = blockIdx.y * 128;
    const int colBase = blockIdx.x * 128;
    const int wave = tid >> 6, lane = tid & 63;
    const int wm = (wave >> 1) * 64, wn = (wave & 1) * 64;
    const int lr = lane & 15, kq = lane >> 4;

    f32x4 ag[4][4] = {};
    f32x4 au[4][4] = {};
    const bf16* Ab = A + (size_t)rowBase * K;
    const bf16* Gb = Wg + (size_t)colBase * K;
    const bf16* Ub = Wu + (size_t)colBase * K;

    for (int k0 = 0; k0 < K; k0 += BK) {
        #pragma unroll
        for (int it = 0; it < 2; ++it) {
            int c = tid + it * 256;
            int r = c >> 2, sseg = c & 3;
            size_t go = (size_t)r * K + k0 + sseg * 8;
            gload_lds16(Ab + go, &lA[c * 8]);
            gload_lds16(Gb + go, &lG[c * 8]);
            gload_lds16(Ub + go, &lU[c * 8]);
        }
        __syncthreads();
        bf16x8 af[4], gf[4], uf[4];
        #pragma unroll
        for (int i = 0; i < 4; ++i) {
            af[i] = *(const bf16x8*)&lA[(wm + i * 16 + lr) * BK + kq * 8];
            gf[i] = *(const bf16x8*)&lG[(wn + i * 16 + lr) * BK + kq * 8];
            uf[i] = *(const bf16x8*)&lU[(wn + i * 16 + lr) * BK + kq * 8];
        }
        #pragma unroll
        for (int mi = 0; mi < 4; ++mi)
            #pragma unroll
            for (int ni = 0; ni < 4; ++ni) {
                ag[mi][ni] = __builtin_amdgcn_mfma_f32_16x16x32_bf16(
                    af[mi], gf[ni], ag[mi][ni], 0, 0, 0);
                au[mi][ni] = __builtin_amdgcn_mfma_f32_16x16x32_bf16(
                    af[mi], uf[ni], au[mi][ni], 0, 0, 0);
            }
        __syncthreads();
    }
    const int rq = lane >> 4, cn = lane & 15;
    #pragma unroll
    for (int mi = 0; mi < 4; ++mi) {
        #pragma unroll
        for (int ni = 0; ni < 4; ++ni) {
            int col = colBase + wn + ni * 16 + cn;
            #pragma unroll
            for (int r = 0; r < 4; ++r) {
                int row = rowBase + wm + mi * 16 + rq * 4 + r;
                float g = ag[mi][ni][r];
                float u = au[mi][ni][r];
                float sg = g / (1.0f + __expf(-g));  // silu; g<<0 -> 0 ok
                out[(size_t)row * N + col] = (bf16)(sg * u);
            }
        }
    }
}

// ---------------------------------------------------------------------------
extern "C" void kernel_launch(void* const* d_in, const int* in_sizes, int n_in,
                              void* d_out, int out_size, void* d_ws, size_t ws_size,
                              hipStream_t stream) {
    const float* x      = (const float*)d_in[0];
    // d_in[1] = positions (unused by the reference math)
    const float* in_w   = (const float*)d_in[2];
    const float* post_w = (const float*)d_in[3];
    const float* Wq     = (const float*)d_in[4];
    const float* Wo     = (const float*)d_in[5];
    const float* Wg     = (const float*)d_in[6];
    const float* Wu     = (const float*)d_in[7];
    const float* Wd     = (const float*)d_in[8];

    // Workspace layout (244 MB; buffers aliased across the serial stream):
    char* ws = (char*)d_ws;
    bf16*  X    = (bf16*)(ws + 0);           // 16.8MB: h_norm, later h_post
    bf16*  Yq   = (bf16*)(ws + 16777216);    // 16.8MB: q (bf16)
    float* hid  = (float*)(ws + 33554432);   // 33.6MB: hidden (fp32 residual)
    bf16*  gu   = (bf16*)(ws + 67108864);    // 90.2MB: silu(g)*u, padded
    bf16*  w0   = (bf16*)(ws + 157286400);   // 45.1MB: Wg bf16, later Wd bf16
    bf16*  w1   = (bf16*)(ws + 202375168);   // 45.1MB: Wu bf16
    bf16*  wsm  = (bf16*)(ws + 247463936);   // 8.4MB : Wq bf16, later Wo bf16

    const int nGU  = INTER_P * HID;          // 22,544,384 (mult of 4)
    const int nGUs = INTER * HID;            // 10,944*2048
    const int nSq  = HID * HID;              // 4,194,304

    // weight conversions (fp32 -> bf16, padded); all serial on stream
    conv_pad<<<nGU / 4 / 256, 256, 0, stream>>>(Wg, w0, nGUs, nGU);
    conv_pad<<<nGU / 4 / 256, 256, 0, stream>>>(Wu, w1, nGUs, nGU);
    conv_pad<<<nSq / 4 / 256, 256, 0, stream>>>(Wq, wsm, nSq, nSq);

    // h_norm = rmsnorm(x) * in_w
    rmsnorm_k<<<TOK, 256, 0, stream>>>(x, in_w, X);
    // q = h_norm @ Wq^T  (bf16 out)
    gemm_bt<0><<<dim3(HID / 128, TOK / 128), 256, 0, stream>>>(
        X, wsm, nullptr, Yq, HID, HID);
    // Wo conversion reuses Wq's slot (Wq dead after gemm above)
    conv_pad<<<nSq / 4 / 256, 256, 0, stream>>>(Wo, wsm, nSq, nSq);
    // hidden = x + q @ Wo^T  (fp32 out)
    gemm_bt<1><<<dim3(HID / 128, TOK / 128), 256, 0, stream>>>(
        Yq, wsm, x, hid, HID, HID);
    // h_post = rmsnorm(hidden) * post_w (reuses X)
    rmsnorm_k<<<TOK, 256, 0, stream>>>(hid, post_w, X);
    // gu = silu(h_post @ Wg^T) * (h_post @ Wu^T)   [N padded to 11008]
    gemm_gu_k<<<dim3(INTER_P / 128, TOK / 128), 256, 0, stream>>>(
        X, w0, w1, gu, INTER_P, HID);
    // Wd conversion reuses Wg's slot (Wg dead after gemm_gu)
    conv_wd<<<nGU / 4 / 256, 256, 0, stream>>>(Wd, w0);
    // out = hidden + gu @ Wd^T  (pad cols of gu are 0 -> exact)
    gemm_bt<1><<<dim3(HID / 128, TOK / 128), 256, 0, stream>>>(
        gu, w0, hid, (float*)d_out, HID, INTER_P);
}

// Round 2
// 1201.283 us; speedup vs baseline: 1.0224x; 1.0224x over previous
//
#include <hip/hip_runtime.h>
#include <hip/hip_bf16.h>
#include <stdint.h>

// ---------------------------------------------------------------------------
// DeepseekV2 decoder layer, bf16 MFMA path, round 2.
// R1 post-mortem: gemm_gu latency-bound (MfmaUtil 31%, occ 21%) because
// 128-acc/wave => 2 waves/SIMD. Fix: 512-thr blocks, wave=64x32 subtile
// (acc 32-64 regs/wave, 4 waves/SIMD => 2 blocks/CU co-resident), plus
// XOR-swizzled LDS chunks to kill the 8-way ds_read_b128 bank conflicts.
// ---------------------------------------------------------------------------

typedef __bf16 bf16;
typedef bf16 bf16x8 __attribute__((ext_vector_type(8)));
typedef bf16 bf16x4 __attribute__((ext_vector_type(4)));
typedef float f32x4 __attribute__((ext_vector_type(4)));

#define HID     2048
#define TOK     4096
#define INTER   10944
#define INTER_P 11008   // padded to multiple of 128; pad region is zeros
#define BK      32

__device__ __forceinline__ void gload_lds16(const bf16* g, bf16* l) {
    __builtin_amdgcn_global_load_lds(
        (const __attribute__((address_space(1))) void*)g,
        (__attribute__((address_space(3))) void*)l, 16, 0, 0);
}

// Swizzle: 8KB tile = 512 chunks of 16B; chunk c stores global (row r=c>>2,
// seg s=(c&3)^((r>>1)&3)). Data (r,s) lives at chunk r*4 + (s^((r>>1)&3)).
// Frag-read slot = (4*lr + swz) mod 8 covers all 8 slots per 8 lanes ->
// 2 lanes/slot = free (m136). Write side is lane-contiguous (async DMA).
__device__ __forceinline__ int swz_chunk(int r, int s) {
    return r * 4 + (s ^ ((r >> 1) & 3));
}

// ---------------------------------------------------------------------------
// fp32 -> bf16 conversion with zero tail (row padding for Wg/Wu).
// ---------------------------------------------------------------------------
__global__ __launch_bounds__(256) void conv_pad(const float* __restrict__ src,
                                                bf16* __restrict__ dst,
                                                int n_src, int n_dst) {
    int i = (blockIdx.x * 256 + threadIdx.x) * 4;
    if (i >= n_dst) return;
    float4 v = make_float4(0.f, 0.f, 0.f, 0.f);
    if (i < n_src) v = *(const float4*)(src + i);
    bf16x4 o;
    o[0] = (bf16)v.x; o[1] = (bf16)v.y; o[2] = (bf16)v.z; o[3] = (bf16)v.w;
    *(bf16x4*)(dst + i) = o;
}

// Wd [2048,10944] -> [2048,11008], columns padded with zeros.
__global__ __launch_bounds__(256) void conv_wd(const float* __restrict__ src,
                                               bf16* __restrict__ dst) {
    int i = (blockIdx.x * 256 + threadIdx.x) * 4;
    if (i >= HID * INTER_P) return;
    int row = i / INTER_P;
    int col = i - row * INTER_P;
    float4 v = make_float4(0.f, 0.f, 0.f, 0.f);
    if (col < INTER)
        v = *(const float4*)(src + (size_t)row * INTER + col);
    bf16x4 o;
    o[0] = (bf16)v.x; o[1] = (bf16)v.y; o[2] = (bf16)v.z; o[3] = (bf16)v.w;
    *(bf16x4*)(dst + i) = o;
}

// ---------------------------------------------------------------------------
// RMSNorm: one block per row of 2048 fp32, emit bf16 * w.
// ---------------------------------------------------------------------------
__global__ __launch_bounds__(256) void rmsnorm_k(const float* __restrict__ x,
                                                 const float* __restrict__ w,
                                                 bf16* __restrict__ out) {
    const int row = blockIdx.x;
    const int tid = threadIdx.x;
    const float* xr = x + (size_t)row * HID + tid * 8;
    float4 v0 = *(const float4*)(xr);
    float4 v1 = *(const float4*)(xr + 4);
    float s = v0.x * v0.x + v0.y * v0.y + v0.z * v0.z + v0.w * v0.w +
              v1.x * v1.x + v1.y * v1.y + v1.z * v1.z + v1.w * v1.w;
    #pragma unroll
    for (int o = 32; o > 0; o >>= 1) s += __shfl_down(s, o);
    __shared__ float red[4];
    if ((tid & 63) == 0) red[tid >> 6] = s;
    __syncthreads();
    float tot = red[0] + red[1] + red[2] + red[3];
    float scale = rsqrtf(tot * (1.0f / (float)HID) + 1e-6f);
    float4 w0 = *(const float4*)(w + tid * 8);
    float4 w1 = *(const float4*)(w + tid * 8 + 4);
    bf16x8 o8;
    o8[0] = (bf16)(v0.x * scale * w0.x);
    o8[1] = (bf16)(v0.y * scale * w0.y);
    o8[2] = (bf16)(v0.z * scale * w0.z);
    o8[3] = (bf16)(v0.w * scale * w0.w);
    o8[4] = (bf16)(v1.x * scale * w1.x);
    o8[5] = (bf16)(v1.y * scale * w1.y);
    o8[6] = (bf16)(v1.z * scale * w1.z);
    o8[7] = (bf16)(v1.w * scale * w1.w);
    *(bf16x8*)(out + (size_t)row * HID + tid * 8) = o8;
}

// ---------------------------------------------------------------------------
// GEMM C[M,N] = A[M,K] * W[N,K]^T, 512 threads, 128x128 tile, BK=32.
// 8 waves in 2x4: wave owns 64x32. acc = 4x2 f32x4 = 32 regs/wave.
// EPI=0: bf16 store. EPI=1: fp32 res[idx]+acc store.
// ---------------------------------------------------------------------------
template <int EPI>
__global__ __launch_bounds__(512, 4) void gemm_bt5(const bf16* __restrict__ A,
                                                   const bf16* __restrict__ W,
                                                   const float* __restrict__ res,
                                                   void* __restrict__ out,
                                                   int N, int K) {
    __shared__ bf16 lA[128 * BK];
    __shared__ bf16 lW[128 * BK];
    const int tid = threadIdx.x;
    const int rowBase = blockIdx.y * 128;
    const int colBase = blockIdx.x * 128;
    const int wave = tid >> 6, lane = tid & 63;
    const int wm = (wave >> 2) * 64, wn = (wave & 3) * 32;
    const int lr = lane & 15, kq = lane >> 4;

    f32x4 acc[4][2] = {};
    const bf16* Ab = A + (size_t)rowBase * K;
    const bf16* Wb = W + (size_t)colBase * K;

    // staging: chunk c = tid (512 chunks per 8KB tile), swizzled placement
    const int sr = tid >> 2;
    const int ss = (tid & 3) ^ ((sr >> 1) & 3);
    const size_t goff = (size_t)sr * K + ss * 8;

    // frag read offsets (element idx): row*32 + (kq ^ ((row>>1)&3))*8
    int aoff[4], woff[2];
    #pragma unroll
    for (int i = 0; i < 4; ++i) {
        int r = wm + i * 16 + lr;
        aoff[i] = r * BK + (kq ^ ((r >> 1) & 3)) * 8;
    }
    #pragma unroll
    for (int i = 0; i < 2; ++i) {
        int r = wn + i * 16 + lr;
        woff[i] = r * BK + (kq ^ ((r >> 1) & 3)) * 8;
    }

    for (int k0 = 0; k0 < K; k0 += BK) {
        gload_lds16(Ab + goff + k0, &lA[tid * 8]);
        gload_lds16(Wb + goff + k0, &lW[tid * 8]);
        __syncthreads();
        bf16x8 af[4], wf[2];
        #pragma unroll
        for (int i = 0; i < 4; ++i) af[i] = *(const bf16x8*)&lA[aoff[i]];
        #pragma unroll
        for (int i = 0; i < 2; ++i) wf[i] = *(const bf16x8*)&lW[woff[i]];
        #pragma unroll
        for (int mi = 0; mi < 4; ++mi)
            #pragma unroll
            for (int ni = 0; ni < 2; ++ni)
                acc[mi][ni] = __builtin_amdgcn_mfma_f32_16x16x32_bf16(
                    af[mi], wf[ni], acc[mi][ni], 0, 0, 0);
        __syncthreads();
    }
    // C/D layout: col = lane&15, row = (lane>>4)*4 + reg  [m89/m91]
    const int rq = lane >> 4, cn = lane & 15;
    #pragma unroll
    for (int mi = 0; mi < 4; ++mi) {
        #pragma unroll
        for (int ni = 0; ni < 2; ++ni) {
            int col = colBase + wn + ni * 16 + cn;
            #pragma unroll
            for (int r = 0; r < 4; ++r) {
                int row = rowBase + wm + mi * 16 + rq * 4 + r;
                size_t idx = (size_t)row * N + col;
                float v = acc[mi][ni][r];
                if (EPI == 0) ((bf16*)out)[idx] = (bf16)v;
                else          ((float*)out)[idx] = res[idx] + v;
            }
        }
    }
}

// ---------------------------------------------------------------------------
// Fused gate/up: gu[t,i] = silu(A Wg^T) * (A Wu^T), 512 threads, 128x128
// tile, wave owns 64x32 of BOTH outputs (acc 2x4x2 f32x4 = 64 regs/wave).
// ---------------------------------------------------------------------------
__global__ __launch_bounds__(512, 4) void gemm_gu5(const bf16* __restrict__ A,
                                                   const bf16* __restrict__ Wg,
                                                   const bf16* __restrict__ Wu,
                                                   bf16* __restrict__ out,
                                                   int N, int K) {
    __shared__ bf16 lA[128 * BK];
    __shared__ bf16 lG[128 * BK];
    __shared__ bf16 lU[128 * BK];
    const int tid = threadIdx.x;
    const int rowBase = blockIdx.y * 128;
    const int colBase = blockIdx.x * 128;
    const int wave = tid >> 6, lane = tid & 63;
    const int wm = (wave >> 2) * 64, wn = (wave & 3) * 32;
    const int lr = lane & 15, kq = lane >> 4;

    f32x4 ag[4][2] = {};
    f32x4 au[4][2] = {};
    const bf16* Ab = A + (size_t)rowBase * K;
    const bf16* Gb = Wg + (size_t)colBase * K;
    const bf16* Ub = Wu + (size_t)colBase * K;

    const int sr = tid >> 2;
    const int ss = (tid & 3) ^ ((sr >> 1) & 3);
    const size_t goff = (size_t)sr * K + ss * 8;

    int aoff[4], boff[2];
    #pragma unroll
    for (int i = 0; i < 4; ++i) {
        int r = wm + i * 16 + lr;
        aoff[i] = r * BK + (kq ^ ((r >> 1) & 3)) * 8;
    }
    #pragma unroll
    for (int i = 0; i < 2; ++i) {
        int r = wn + i * 16 + lr;
        boff[i] = r * BK + (kq ^ ((r >> 1) & 3)) * 8;
    }

    for (int k0 = 0; k0 < K; k0 += BK) {
        gload_lds16(Ab + goff + k0, &lA[tid * 8]);
        gload_lds16(Gb + goff + k0, &lG[tid * 8]);
        gload_lds16(Ub + goff + k0, &lU[tid * 8]);
        __syncthreads();
        bf16x8 af[4], gf[2], uf[2];
        #pragma unroll
        for (int i = 0; i < 4; ++i) af[i] = *(const bf16x8*)&lA[aoff[i]];
        #pragma unroll
        for (int i = 0; i < 2; ++i) {
            gf[i] = *(const bf16x8*)&lG[boff[i]];
            uf[i] = *(const bf16x8*)&lU[boff[i]];
        }
        #pragma unroll
        for (int mi = 0; mi < 4; ++mi)
            #pragma unroll
            for (int ni = 0; ni < 2; ++ni) {
                ag[mi][ni] = __builtin_amdgcn_mfma_f32_16x16x32_bf16(
                    af[mi], gf[ni], ag[mi][ni], 0, 0, 0);
                au[mi][ni] = __builtin_amdgcn_mfma_f32_16x16x32_bf16(
                    af[mi], uf[ni], au[mi][ni], 0, 0, 0);
            }
        __syncthreads();
    }
    const int rq = lane >> 4, cn = lane & 15;
    #pragma unroll
    for (int mi = 0; mi < 4; ++mi) {
        #pragma unroll
        for (int ni = 0; ni < 2; ++ni) {
            int col = colBase + wn + ni * 16 + cn;
            #pragma unroll
            for (int r = 0; r < 4; ++r) {
                int row = rowBase + wm + mi * 16 + rq * 4 + r;
                float g = ag[mi][ni][r];
                float u = au[mi][ni][r];
                float sg = g / (1.0f + __expf(-g));  // silu
                out[(size_t)row * N + col] = (bf16)(sg * u);
            }
        }
    }
}

// ---------------------------------------------------------------------------
extern "C" void kernel_launch(void* const* d_in, const int* in_sizes, int n_in,
                              void* d_out, int out_size, void* d_ws, size_t ws_size,
                              hipStream_t stream) {
    const float* x      = (const float*)d_in[0];
    const float* in_w   = (const float*)d_in[2];
    const float* post_w = (const float*)d_in[3];
    const float* Wq     = (const float*)d_in[4];
    const float* Wo     = (const float*)d_in[5];
    const float* Wg     = (const float*)d_in[6];
    const float* Wu     = (const float*)d_in[7];
    const float* Wd     = (const float*)d_in[8];

    char* ws = (char*)d_ws;
    bf16*  X    = (bf16*)(ws + 0);           // 16.8MB: h_norm, later h_post
    bf16*  Yq   = (bf16*)(ws + 16777216);    // 16.8MB: q (bf16)
    float* hid  = (float*)(ws + 33554432);   // 33.6MB: hidden (fp32 residual)
    bf16*  gu   = (bf16*)(ws + 67108864);    // 90.2MB: silu(g)*u, padded
    bf16*  w0   = (bf16*)(ws + 157286400);   // 45.1MB: Wg bf16, later Wd bf16
    bf16*  w1   = (bf16*)(ws + 202375168);   // 45.1MB: Wu bf16
    bf16*  wsm  = (bf16*)(ws + 247463936);   // 8.4MB : Wq bf16, later Wo bf16

    const int nGU  = INTER_P * HID;
    const int nGUs = INTER * HID;
    const int nSq  = HID * HID;

    conv_pad<<<nGU / 4 / 256, 256, 0, stream>>>(Wg, w0, nGUs, nGU);
    conv_pad<<<nGU / 4 / 256, 256, 0, stream>>>(Wu, w1, nGUs, nGU);
    conv_pad<<<nSq / 4 / 256, 256, 0, stream>>>(Wq, wsm, nSq, nSq);

    rmsnorm_k<<<TOK, 256, 0, stream>>>(x, in_w, X);
    // q = h_norm @ Wq^T
    gemm_bt5<0><<<dim3(HID / 128, TOK / 128), 512, 0, stream>>>(
        X, wsm, nullptr, Yq, HID, HID);
    conv_pad<<<nSq / 4 / 256, 256, 0, stream>>>(Wo, wsm, nSq, nSq);
    // hidden = x + q @ Wo^T
    gemm_bt5<1><<<dim3(HID / 128, TOK / 128), 512, 0, stream>>>(
        Yq, wsm, x, hid, HID, HID);
    rmsnorm_k<<<TOK, 256, 0, stream>>>(hid, post_w, X);
    // gu = silu(h_post @ Wg^T) * (h_post @ Wu^T)
    gemm_gu5<<<dim3(INTER_P / 128, TOK / 128), 512, 0, stream>>>(
        X, w0, w1, gu, INTER_P, HID);
    conv_wd<<<nGU / 4 / 256, 256, 0, stream>>>(Wd, w0);
    // out = hidden + gu @ Wd^T
    gemm_bt5<1><<<dim3(HID / 128, TOK / 128), 512, 0, stream>>>(
        gu, w0, hid, (float*)d_out, HID, INTER_P);
}

// Round 3
// 1093.868 us; speedup vs baseline: 1.1228x; 1.0982x over previous
//
#include <hip/hip_runtime.h>
#include <hip/hip_bf16.h>
#include <stdint.h>

// ---------------------------------------------------------------------------
// DeepseekV2 decoder layer, bf16 MFMA path, round 3.
// R2 post-mortem: gemm_gu HBM-bound on weight re-fetch (FETCH 1.6GB vs
// 152MB unique; 3.5TB/s sustained ~= dur). Cause: blockIdx.x was the N
// (column/weight-panel) dim, so the resident-block window swept all 86
// weight panels per row-block. Fix: blockIdx.x = M-tile (fastest), so
// consecutive blocks share one weight panel -> weights read from HBM ~once.
// ---------------------------------------------------------------------------

typedef __bf16 bf16;
typedef bf16 bf16x8 __attribute__((ext_vector_type(8)));
typedef bf16 bf16x4 __attribute__((ext_vector_type(4)));
typedef float f32x4 __attribute__((ext_vector_type(4)));

#define HID     2048
#define TOK     4096
#define INTER   10944
#define INTER_P 11008   // padded to multiple of 128; pad region is zeros
#define BK      32

__device__ __forceinline__ void gload_lds16(const bf16* g, bf16* l) {
    __builtin_amdgcn_global_load_lds(
        (const __attribute__((address_space(1))) void*)g,
        (__attribute__((address_space(3))) void*)l, 16, 0, 0);
}

// ---------------------------------------------------------------------------
// fp32 -> bf16 conversion with zero tail (row padding for Wg/Wu).
// ---------------------------------------------------------------------------
__global__ __launch_bounds__(256) void conv_pad(const float* __restrict__ src,
                                                bf16* __restrict__ dst,
                                                int n_src, int n_dst) {
    int i = (blockIdx.x * 256 + threadIdx.x) * 4;
    if (i >= n_dst) return;
    float4 v = make_float4(0.f, 0.f, 0.f, 0.f);
    if (i < n_src) v = *(const float4*)(src + i);
    bf16x4 o;
    o[0] = (bf16)v.x; o[1] = (bf16)v.y; o[2] = (bf16)v.z; o[3] = (bf16)v.w;
    *(bf16x4*)(dst + i) = o;
}

// Wd [2048,10944] -> [2048,11008], columns padded with zeros.
__global__ __launch_bounds__(256) void conv_wd(const float* __restrict__ src,
                                               bf16* __restrict__ dst) {
    int i = (blockIdx.x * 256 + threadIdx.x) * 4;
    if (i >= HID * INTER_P) return;
    int row = i / INTER_P;
    int col = i - row * INTER_P;
    float4 v = make_float4(0.f, 0.f, 0.f, 0.f);
    if (col < INTER)
        v = *(const float4*)(src + (size_t)row * INTER + col);
    bf16x4 o;
    o[0] = (bf16)v.x; o[1] = (bf16)v.y; o[2] = (bf16)v.z; o[3] = (bf16)v.w;
    *(bf16x4*)(dst + i) = o;
}

// ---------------------------------------------------------------------------
// RMSNorm: one block per row of 2048 fp32, emit bf16 * w.
// ---------------------------------------------------------------------------
__global__ __launch_bounds__(256) void rmsnorm_k(const float* __restrict__ x,
                                                 const float* __restrict__ w,
                                                 bf16* __restrict__ out) {
    const int row = blockIdx.x;
    const int tid = threadIdx.x;
    const float* xr = x + (size_t)row * HID + tid * 8;
    float4 v0 = *(const float4*)(xr);
    float4 v1 = *(const float4*)(xr + 4);
    float s = v0.x * v0.x + v0.y * v0.y + v0.z * v0.z + v0.w * v0.w +
              v1.x * v1.x + v1.y * v1.y + v1.z * v1.z + v1.w * v1.w;
    #pragma unroll
    for (int o = 32; o > 0; o >>= 1) s += __shfl_down(s, o);
    __shared__ float red[4];
    if ((tid & 63) == 0) red[tid >> 6] = s;
    __syncthreads();
    float tot = red[0] + red[1] + red[2] + red[3];
    float scale = rsqrtf(tot * (1.0f / (float)HID) + 1e-6f);
    float4 w0 = *(const float4*)(w + tid * 8);
    float4 w1 = *(const float4*)(w + tid * 8 + 4);
    bf16x8 o8;
    o8[0] = (bf16)(v0.x * scale * w0.x);
    o8[1] = (bf16)(v0.y * scale * w0.y);
    o8[2] = (bf16)(v0.z * scale * w0.z);
    o8[3] = (bf16)(v0.w * scale * w0.w);
    o8[4] = (bf16)(v1.x * scale * w1.x);
    o8[5] = (bf16)(v1.y * scale * w1.y);
    o8[6] = (bf16)(v1.z * scale * w1.z);
    o8[7] = (bf16)(v1.w * scale * w1.w);
    *(bf16x8*)(out + (size_t)row * HID + tid * 8) = o8;
}

// ---------------------------------------------------------------------------
// GEMM C[M,N] = A[M,K] * W[N,K]^T, 512 threads, 128x128 tile, BK=32.
// GRID: x = M-tile (fastest-varying: weight-panel locality), y = N-panel.
// 8 waves in 2x4: wave owns 64x32. acc = 4x2 f32x4 = 32 regs/wave.
// EPI=0: bf16 store. EPI=1: fp32 res[idx]+acc store.
// ---------------------------------------------------------------------------
template <int EPI>
__global__ __launch_bounds__(512, 4) void gemm_bt5(const bf16* __restrict__ A,
                                                   const bf16* __restrict__ W,
                                                   const float* __restrict__ res,
                                                   void* __restrict__ out,
                                                   int N, int K) {
    __shared__ bf16 lA[128 * BK];
    __shared__ bf16 lW[128 * BK];
    const int tid = threadIdx.x;
    const int rowBase = blockIdx.x * 128;   // M fastest
    const int colBase = blockIdx.y * 128;   // weight panel
    const int wave = tid >> 6, lane = tid & 63;
    const int wm = (wave >> 2) * 64, wn = (wave & 3) * 32;
    const int lr = lane & 15, kq = lane >> 4;

    f32x4 acc[4][2] = {};
    const bf16* Ab = A + (size_t)rowBase * K;
    const bf16* Wb = W + (size_t)colBase * K;

    // staging: chunk c = tid (512 chunks per 8KB tile), swizzled placement
    const int sr = tid >> 2;
    const int ss = (tid & 3) ^ ((sr >> 1) & 3);
    const size_t goff = (size_t)sr * K + ss * 8;

    // frag read offsets (element idx): row*32 + (kq ^ ((row>>1)&3))*8
    int aoff[4], woff[2];
    #pragma unroll
    for (int i = 0; i < 4; ++i) {
        int r = wm + i * 16 + lr;
        aoff[i] = r * BK + (kq ^ ((r >> 1) & 3)) * 8;
    }
    #pragma unroll
    for (int i = 0; i < 2; ++i) {
        int r = wn + i * 16 + lr;
        woff[i] = r * BK + (kq ^ ((r >> 1) & 3)) * 8;
    }

    for (int k0 = 0; k0 < K; k0 += BK) {
        gload_lds16(Ab + goff + k0, &lA[tid * 8]);
        gload_lds16(Wb + goff + k0, &lW[tid * 8]);
        __syncthreads();
        bf16x8 af[4], wf[2];
        #pragma unroll
        for (int i = 0; i < 4; ++i) af[i] = *(const bf16x8*)&lA[aoff[i]];
        #pragma unroll
        for (int i = 0; i < 2; ++i) wf[i] = *(const bf16x8*)&lW[woff[i]];
        #pragma unroll
        for (int mi = 0; mi < 4; ++mi)
            #pragma unroll
            for (int ni = 0; ni < 2; ++ni)
                acc[mi][ni] = __builtin_amdgcn_mfma_f32_16x16x32_bf16(
                    af[mi], wf[ni], acc[mi][ni], 0, 0, 0);
        __syncthreads();
    }
    // C/D layout: col = lane&15, row = (lane>>4)*4 + reg  [m89/m91]
    const int rq = lane >> 4, cn = lane & 15;
    #pragma unroll
    for (int mi = 0; mi < 4; ++mi) {
        #pragma unroll
        for (int ni = 0; ni < 2; ++ni) {
            int col = colBase + wn + ni * 16 + cn;
            #pragma unroll
            for (int r = 0; r < 4; ++r) {
                int row = rowBase + wm + mi * 16 + rq * 4 + r;
                size_t idx = (size_t)row * N + col;
                float v = acc[mi][ni][r];
                if (EPI == 0) ((bf16*)out)[idx] = (bf16)v;
                else          ((float*)out)[idx] = res[idx] + v;
            }
        }
    }
}

// ---------------------------------------------------------------------------
// Fused gate/up: gu[t,i] = silu(A Wg^T) * (A Wu^T), 512 threads, 128x128
// tile, wave owns 64x32 of BOTH outputs. GRID: x = M-tile, y = N-panel.
// ---------------------------------------------------------------------------
__global__ __launch_bounds__(512, 4) void gemm_gu5(const bf16* __restrict__ A,
                                                   const bf16* __restrict__ Wg,
                                                   const bf16* __restrict__ Wu,
                                                   bf16* __restrict__ out,
                                                   int N, int K) {
    __shared__ bf16 lA[128 * BK];
    __shared__ bf16 lG[128 * BK];
    __shared__ bf16 lU[128 * BK];
    const int tid = threadIdx.x;
    const int rowBase = blockIdx.x * 128;   // M fastest
    const int colBase = blockIdx.y * 128;   // weight panel
    const int wave = tid >> 6, lane = tid & 63;
    const int wm = (wave >> 2) * 64, wn = (wave & 3) * 32;
    const int lr = lane & 15, kq = lane >> 4;

    f32x4 ag[4][2] = {};
    f32x4 au[4][2] = {};
    const bf16* Ab = A + (size_t)rowBase * K;
    const bf16* Gb = Wg + (size_t)colBase * K;
    const bf16* Ub = Wu + (size_t)colBase * K;

    const int sr = tid >> 2;
    const int ss = (tid & 3) ^ ((sr >> 1) & 3);
    const size_t goff = (size_t)sr * K + ss * 8;

    int aoff[4], boff[2];
    #pragma unroll
    for (int i = 0; i < 4; ++i) {
        int r = wm + i * 16 + lr;
        aoff[i] = r * BK + (kq ^ ((r >> 1) & 3)) * 8;
    }
    #pragma unroll
    for (int i = 0; i < 2; ++i) {
        int r = wn + i * 16 + lr;
        boff[i] = r * BK + (kq ^ ((r >> 1) & 3)) * 8;
    }

    for (int k0 = 0; k0 < K; k0 += BK) {
        gload_lds16(Ab + goff + k0, &lA[tid * 8]);
        gload_lds16(Gb + goff + k0, &lG[tid * 8]);
        gload_lds16(Ub + goff + k0, &lU[tid * 8]);
        __syncthreads();
        bf16x8 af[4], gf[2], uf[2];
        #pragma unroll
        for (int i = 0; i < 4; ++i) af[i] = *(const bf16x8*)&lA[aoff[i]];
        #pragma unroll
        for (int i = 0; i < 2; ++i) {
            gf[i] = *(const bf16x8*)&lG[boff[i]];
            uf[i] = *(const bf16x8*)&lU[boff[i]];
        }
        #pragma unroll
        for (int mi = 0; mi < 4; ++mi)
            #pragma unroll
            for (int ni = 0; ni < 2; ++ni) {
                ag[mi][ni] = __builtin_amdgcn_mfma_f32_16x16x32_bf16(
                    af[mi], gf[ni], ag[mi][ni], 0, 0, 0);
                au[mi][ni] = __builtin_amdgcn_mfma_f32_16x16x32_bf16(
                    af[mi], uf[ni], au[mi][ni], 0, 0, 0);
            }
        __syncthreads();
    }
    const int rq = lane >> 4, cn = lane & 15;
    #pragma unroll
    for (int mi = 0; mi < 4; ++mi) {
        #pragma unroll
        for (int ni = 0; ni < 2; ++ni) {
            int col = colBase + wn + ni * 16 + cn;
            #pragma unroll
            for (int r = 0; r < 4; ++r) {
                int row = rowBase + wm + mi * 16 + rq * 4 + r;
                float g = ag[mi][ni][r];
                float u = au[mi][ni][r];
                float sg = g / (1.0f + __expf(-g));  // silu
                out[(size_t)row * N + col] = (bf16)(sg * u);
            }
        }
    }
}

// ---------------------------------------------------------------------------
extern "C" void kernel_launch(void* const* d_in, const int* in_sizes, int n_in,
                              void* d_out, int out_size, void* d_ws, size_t ws_size,
                              hipStream_t stream) {
    const float* x      = (const float*)d_in[0];
    const float* in_w   = (const float*)d_in[2];
    const float* post_w = (const float*)d_in[3];
    const float* Wq     = (const float*)d_in[4];
    const float* Wo     = (const float*)d_in[5];
    const float* Wg     = (const float*)d_in[6];
    const float* Wu     = (const float*)d_in[7];
    const float* Wd     = (const float*)d_in[8];

    char* ws = (char*)d_ws;
    bf16*  X    = (bf16*)(ws + 0);           // 16.8MB: h_norm, later h_post
    bf16*  Yq   = (bf16*)(ws + 16777216);    // 16.8MB: q (bf16)
    float* hid  = (float*)(ws + 33554432);   // 33.6MB: hidden (fp32 residual)
    bf16*  gu   = (bf16*)(ws + 67108864);    // 90.2MB: silu(g)*u, padded
    bf16*  w0   = (bf16*)(ws + 157286400);   // 45.1MB: Wg bf16, later Wd bf16
    bf16*  w1   = (bf16*)(ws + 202375168);   // 45.1MB: Wu bf16
    bf16*  wsm  = (bf16*)(ws + 247463936);   // 8.4MB : Wq bf16, later Wo bf16

    const int nGU  = INTER_P * HID;
    const int nGUs = INTER * HID;
    const int nSq  = HID * HID;

    conv_pad<<<nGU / 4 / 256, 256, 0, stream>>>(Wg, w0, nGUs, nGU);
    conv_pad<<<nGU / 4 / 256, 256, 0, stream>>>(Wu, w1, nGUs, nGU);
    conv_pad<<<nSq / 4 / 256, 256, 0, stream>>>(Wq, wsm, nSq, nSq);

    rmsnorm_k<<<TOK, 256, 0, stream>>>(x, in_w, X);
    // q = h_norm @ Wq^T    (grid: x = M-tiles, y = N-panels)
    gemm_bt5<0><<<dim3(TOK / 128, HID / 128), 512, 0, stream>>>(
        X, wsm, nullptr, Yq, HID, HID);
    conv_pad<<<nSq / 4 / 256, 256, 0, stream>>>(Wo, wsm, nSq, nSq);
    // hidden = x + q @ Wo^T
    gemm_bt5<1><<<dim3(TOK / 128, HID / 128), 512, 0, stream>>>(
        Yq, wsm, x, hid, HID, HID);
    rmsnorm_k<<<TOK, 256, 0, stream>>>(hid, post_w, X);
    // gu = silu(h_post @ Wg^T) * (h_post @ Wu^T)
    gemm_gu5<<<dim3(TOK / 128, INTER_P / 128), 512, 0, stream>>>(
        X, w0, w1, gu, INTER_P, HID);
    conv_wd<<<nGU / 4 / 256, 256, 0, stream>>>(Wd, w0);
    // out = hidden + gu @ Wd^T
    gemm_bt5<1><<<dim3(TOK / 128, HID / 128), 512, 0, stream>>>(
        gu, w0, hid, (float*)d_out, HID, INTER_P);
}